// Round 1
// baseline (1286.350 us; speedup 1.0000x reference)
//
#include <hip/hip_runtime.h>

#define EPSF 1e-8f
#define BN 4096
#define NF 16384
#define SCALE 12.5f   // c * bandwidth = 0.25 * 50
#define SINV 0.08f    // 1 / 12.5

// ---------------- Kernel 1: gather K rows, compute d_i and w_i = 1/d_i ----
template <bool STORE>
__global__ __launch_bounds__(256) void k_gather_d(
    const float* __restrict__ Kf, const int* __restrict__ idx,
    float* __restrict__ Kb, float* __restrict__ dv, float* __restrict__ wv) {
  const int i = blockIdx.x;
  const int t = threadIdx.x;
  const size_t base = (size_t)idx[i] * (size_t)NF;
  float s = 0.f;
#pragma unroll
  for (int jt = 0; jt < 16; ++jt) {
    const int j = jt * 256 + t;
    const float v = Kf[base + (size_t)idx[j]];
    if (STORE) Kb[(size_t)i * BN + j] = v;
    s += v;
  }
#pragma unroll
  for (int o = 32; o > 0; o >>= 1) s += __shfl_down(s, o, 64);
  __shared__ float red[4];
  if ((t & 63) == 0) red[t >> 6] = s;
  __syncthreads();
  if (t == 0) {
    const float tot = red[0] + red[1] + red[2] + red[3] + EPSF;
    dv[i] = tot;
    wv[i] = 1.0f / tot;
  }
}

// ---------------- Kernel 2: per-row contraction into 8x8 H, loss ----------
template <bool GATHER>
__global__ __launch_bounds__(256) void k_rows(
    const float* __restrict__ Ksrc, const int* __restrict__ idx,
    const float* __restrict__ z, const float* __restrict__ dv,
    const float* __restrict__ wv, float* __restrict__ lossv) {
  const int i = blockIdx.x;
  const int t = threadIdx.x;
  const size_t base = GATHER ? (size_t)idx[i] * (size_t)NF : (size_t)i * BN;

  float vals[45];  // [0..35] = sym outer acc (a<=b), [36..43] = u', [44] = t0
#pragma unroll
  for (int k = 0; k < 45; ++k) vals[k] = 0.f;

  const float4* z4 = (const float4*)z;
  for (int jt = 0; jt < 16; ++jt) {
    const int j = jt * 256 + t;
    const float kv = GATHER ? Ksrc[base + (size_t)idx[j]] : Ksrc[base + j];
    const float kw = kv * wv[j];
    const float4 za = z4[2 * j];
    const float4 zb = z4[2 * j + 1];
    float zz[8] = {za.x, za.y, za.z, za.w, zb.x, zb.y, zb.z, zb.w};
    float q[8];
#pragma unroll
    for (int a = 0; a < 8; ++a) {
      q[a] = kw * zz[a];
      vals[36 + a] += q[a];
    }
    vals[44] += kw;
    int k = 0;
#pragma unroll
    for (int a = 0; a < 8; ++a)
#pragma unroll
      for (int b = a; b < 8; ++b) {
        vals[k] += q[a] * zz[b];
        ++k;
      }
  }

  // reduce 45 values across the block
#pragma unroll
  for (int k = 0; k < 45; ++k) {
    float v = vals[k];
#pragma unroll
    for (int o = 32; o > 0; o >>= 1) v += __shfl_down(v, o, 64);
    vals[k] = v;
  }
  __shared__ float red[4][45];
  if ((t & 63) == 0) {
#pragma unroll
    for (int k = 0; k < 45; ++k) red[t >> 6][k] = vals[k];
  }
  __syncthreads();

  if (t == 0) {
    float S[36], U[8], T0;
#pragma unroll
    for (int k = 0; k < 36; ++k) S[k] = red[0][k] + red[1][k] + red[2][k] + red[3][k];
#pragma unroll
    for (int a = 0; a < 8; ++a)
      U[a] = red[0][36 + a] + red[1][36 + a] + red[2][36 + a] + red[3][36 + a];
    T0 = red[0][44] + red[1][44] + red[2][44] + red[3][44];

    const float di = dv[i];
    const float wi = wv[i];
    const float dt = T0 * wi + EPSF;            // d_tilde_i
    const float alpha = 1.0f / (di * dt * SCALE);

    const float4 za = z4[2 * i];
    const float4 zb = z4[2 * i + 1];
    float zi[8] = {za.x, za.y, za.z, za.w, zb.x, zb.y, zb.z, zb.w};
    float u[8];
#pragma unroll
    for (int a = 0; a < 8; ++a) u[a] = alpha * U[a];

    float trH = 0.f, tr2 = 0.f;
    int k = 0;
#pragma unroll
    for (int a = 0; a < 8; ++a)
#pragma unroll
      for (int b = a; b < 8; ++b) {
        const float H =
            0.5f * (alpha * S[k] + SINV * zi[a] * zi[b] - zi[a] * u[b] - u[a] * zi[b]);
        if (a == b) {
          trH += H;
          tr2 += H * H;
        } else {
          tr2 += 2.f * H * H;
        }
        ++k;
      }
    lossv[i] = tr2 - 2.f * trH;
  }
}

// ---------------- Kernel 3: final mean + n ---------------------------------
__global__ __launch_bounds__(256) void k_final(const float* __restrict__ lossv,
                                               float* __restrict__ out) {
  const int t = threadIdx.x;
  float s = 0.f;
  for (int i = t; i < BN; i += 256) s += lossv[i];
#pragma unroll
  for (int o = 32; o > 0; o >>= 1) s += __shfl_down(s, o, 64);
  __shared__ float red[4];
  if ((t & 63) == 0) red[t >> 6] = s;
  __syncthreads();
  if (t == 0) out[0] = (red[0] + red[1] + red[2] + red[3]) / (float)BN + 8.0f;
}

extern "C" void kernel_launch(void* const* d_in, const int* in_sizes, int n_in,
                              void* d_out, int out_size, void* d_ws, size_t ws_size,
                              hipStream_t stream) {
  const float* z = (const float*)d_in[0];
  const float* Kf = (const float*)d_in[1];
  const int* idx = (const int*)d_in[2];
  float* out = (float*)d_out;

  char* ws = (char*)d_ws;
  const size_t kb_bytes = (size_t)BN * BN * sizeof(float);
  const bool store = ws_size >= kb_bytes + 3 * BN * sizeof(float);

  float *Kb, *dv, *wv, *lossv;
  if (store) {
    Kb = (float*)ws;
    dv = (float*)(ws + kb_bytes);
  } else {
    Kb = nullptr;
    dv = (float*)ws;
  }
  wv = dv + BN;
  lossv = wv + BN;

  if (store) {
    k_gather_d<true><<<BN, 256, 0, stream>>>(Kf, idx, Kb, dv, wv);
    k_rows<false><<<BN, 256, 0, stream>>>(Kb, idx, z, dv, wv, lossv);
  } else {
    k_gather_d<false><<<BN, 256, 0, stream>>>(Kf, idx, nullptr, dv, wv);
    k_rows<true><<<BN, 256, 0, stream>>>(Kf, idx, z, dv, wv, lossv);
  }
  k_final<<<1, 256, 0, stream>>>(lossv, out);
}